// Round 5
// baseline (221.532 us; speedup 1.0000x reference)
//
#include <hip/hip_runtime.h>
#include <math.h>

#define C_IN 256
#define P_CH 64
#define H_IMG 128
#define W_IMG 128
#define HW (H_IMG*W_IMG)
#define N_IMG 4
#define K_PROTO 8
#define BN_EPS 1e-5f

typedef unsigned short u16;
typedef __attribute__((ext_vector_type(4))) short bf16x4;
typedef __attribute__((ext_vector_type(8))) short bf16x8;
typedef __attribute__((ext_vector_type(4))) float f32x4;

// workspace layout (float offsets)
#define OFF_WTBF   0                     // 8192 fl = 16384 bf16: W bf16 [n][k], BN-folded
#define OFF_BIASA  8192                  // 64: folded BN shift
#define OFF_PNORM  8256                  // 8: |proto_k|^2
#define OFF_MINMAX 8264                  // 8 uints
#define OFF_MD     8272                  // 65536: min_dist per pixel
#define OFF_ATTN   (OFF_MD + 65536)      // 65536: attention map

__device__ __forceinline__ float silu_f(float x) { return x / (1.f + __expf(-x)); }

__device__ __forceinline__ u16 f2bf(float f) {   // round-to-nearest-even
    union { float f; unsigned u; } v; v.f = f;
    unsigned r = v.u + 0x7fffu + ((v.u >> 16) & 1u);
    return (u16)(r >> 16);
}
__device__ __forceinline__ float bf2f(u16 s) {
    union { unsigned u; float f; } v; v.u = ((unsigned)s) << 16; return v.f;
}

// ---------------- prep: fold BN into bf16 W [n][k], proto norms, minmax init --
__global__ void prep_kernel(const float* __restrict__ w1, const float* __restrict__ bn1,
                            const float* __restrict__ protos, float* __restrict__ ws)
{
    int bx = blockIdx.x, tid = threadIdx.x;
    if (bx < 64) {
        int idx = bx * 256 + tid;          // 16384 = 64 n x 256 k
        int n = idx >> 8, k = idx & 255;
        float sc = bn1[n] * rsqrtf(bn1[192 + n] + BN_EPS);
        ((u16*)(ws + OFF_WTBF))[idx] = f2bf(w1[n * C_IN + k] * sc);
    } else {
        if (tid < 64) {
            float sc = bn1[tid] * rsqrtf(bn1[192 + tid] + BN_EPS);
            ws[OFF_BIASA + tid] = bn1[64 + tid] - bn1[128 + tid] * sc;
        }
        if (tid < 8) {
            float s = 0.f;
            for (int p = 0; p < 64; ++p) { float v = protos[tid * 64 + p]; s += v * v; }
            ws[OFF_PNORM + tid] = s;
        }
        if (tid < 4) {
            unsigned* mm = (unsigned*)(ws + OFF_MINMAX);
            mm[tid * 2]     = 0x7f7fffffu;
            mm[tid * 2 + 1] = 0u;
        }
    }
}

// ---------------- fused: conv1x1(MFMA) + DW3x3 + BN/SiLU + proto-distance ----
// Block = 16x8 output tile; halo = 18x10 = 180 px (p = y*10+x), M padded to 192
// (12 M-tiles, 3/wave). K=256 in 8 chunks of 32, single LDS A buffer + register
// prefetch. h tile kept entirely in LDS (bf16) - no HBM round-trip.
#define HALO_PX 180
#define M_PAD   192
#define LDA     36    // u16 per px row in As
#define LDB     264   // u16 per n row in Bs
#define LDH     200   // u16 per n row in Hs
__global__ __launch_bounds__(256, 2) void fused_front_kernel(
    const float* __restrict__ x, const u16* __restrict__ wtb,
    const float* __restrict__ biasA, const float* __restrict__ dw,
    const float* __restrict__ bn2, const float* __restrict__ protos,
    const float* __restrict__ pnorm, float* __restrict__ md,
    unsigned* __restrict__ minmax)
{
    __shared__ unsigned long long smem8[47616 / 8];
    u16* Bs = (u16*)smem8;               // [64][LDB] = 33792 B
    u16* As = Bs + 64 * LDB;             // [192][LDA] = 13824 B (total 47616)
    u16* Hs = (u16*)smem8;               // [64][LDH] = 25600 B (aliased, post-GEMM)
    float* Pp = (float*)((char*)smem8 + 25600);   // [128][9] partials
    float* mmx = (float*)((char*)smem8 + 30208);  // 8 floats

    int bx = blockIdx.x;
    int img = bx >> 7;
    int t = bx & 127;
    int ty0 = (t >> 4) << 4;   // tile row origin (16 rows)
    int tx0 = (t & 15) << 3;   // tile col origin (8 cols)
    int tid = threadIdx.x;
    int wid = tid >> 6, lane = tid & 63;
    int mm = lane & 15, kb = lane >> 4;

    // ---- stage B (once): thread -> n = tid>>2, k-quarter (tid&3)*64 ----
    {
        int n = tid >> 2, k0 = (tid & 3) * 64;
        const u16* src = wtb + n * 256 + k0;
        u16* dst = Bs + n * LDB + k0;
#pragma unroll
        for (int i = 0; i < 64; i += 4)
            *(ushort4*)(dst + i) = *(const ushort4*)(src + i);
    }
    // ---- zero As pad rows [180,192) : 432 u16 = 216 dwords ----
    if (tid < 216) ((unsigned*)(As + HALO_PX * LDA))[tid] = 0u;

    // ---- staging geometry: cp = tid>>4 -> ch pair {2cp,2cp+1}; pg = tid&15 ----
    int cp = tid >> 4, pg = tid & 15;
    int off[12];
    unsigned wm = 0, vm = 0;   // write mask (p<180), load mask (in image)
#pragma unroll
    for (int i = 0; i < 12; ++i) {
        int p = pg + 16 * i;
        int y = (p * 205) >> 11;       // p/10 for p<192
        int xx = p - y * 10;
        int gy = ty0 - 1 + y, gx = tx0 - 1 + xx;
        bool w = p < HALO_PX;
        bool v = w && gy >= 0 && gy < H_IMG && gx >= 0 && gx < W_IMG;
        if (w) wm |= 1u << i;
        if (v) vm |= 1u << i;
        off[i] = v ? (gy * W_IMG + gx) : 0;
    }
    const float* xim = x + (size_t)img * C_IN * HW;

    // ---- prefetch chunk 0 + write ----
    float f0[12], f1[12];
    {
        const float* xc0 = xim + (size_t)(2 * cp) * HW;
        const float* xc1 = xc0 + HW;
#pragma unroll
        for (int i = 0; i < 12; ++i) {
            f0[i] = (vm >> i & 1) ? xc0[off[i]] : 0.f;
            f1[i] = (vm >> i & 1) ? xc1[off[i]] : 0.f;
        }
#pragma unroll
        for (int i = 0; i < 12; ++i)
            if (wm >> i & 1) {
                ushort2 pk; pk.x = f2bf(f0[i]); pk.y = f2bf(f1[i]);
                *(ushort2*)&As[(pg + 16 * i) * LDA + 2 * cp] = pk;
            }
    }
    __syncthreads();

    f32x4 acc[3][4];
#pragma unroll
    for (int mt = 0; mt < 3; ++mt)
#pragma unroll
        for (int nt = 0; nt < 4; ++nt) acc[mt][nt] = (f32x4){0.f, 0.f, 0.f, 0.f};

    // ---- GEMM over K: 8 chunks of 32 ----
    for (int k = 0; k < 8; ++k) {
        if (k < 7) {
            const float* xc0 = xim + (size_t)((k + 1) * 32 + 2 * cp) * HW;
            const float* xc1 = xc0 + HW;
#pragma unroll
            for (int i = 0; i < 12; ++i) {
                f0[i] = (vm >> i & 1) ? xc0[off[i]] : 0.f;
                f1[i] = (vm >> i & 1) ? xc1[off[i]] : 0.f;
            }
        }

        bf16x8 afrag[3], bfrag[4];
#pragma unroll
        for (int mt = 0; mt < 3; ++mt) {
            const u16* ap = As + ((wid * 3 + mt) * 16 + mm) * LDA + kb * 8;
            bf16x4 lo = *(const bf16x4*)ap;
            bf16x4 hi = *(const bf16x4*)(ap + 4);
            afrag[mt] = __builtin_shufflevector(lo, hi, 0, 1, 2, 3, 4, 5, 6, 7);
        }
#pragma unroll
        for (int nt = 0; nt < 4; ++nt)
            bfrag[nt] = *(const bf16x8*)(Bs + (nt * 16 + mm) * LDB + k * 32 + kb * 8);
#pragma unroll
        for (int mt = 0; mt < 3; ++mt)
#pragma unroll
            for (int nt = 0; nt < 4; ++nt)
                acc[mt][nt] = __builtin_amdgcn_mfma_f32_16x16x32_bf16(
                    afrag[mt], bfrag[nt], acc[mt][nt], 0, 0, 0);
        __syncthreads();

        if (k < 7) {
#pragma unroll
            for (int i = 0; i < 12; ++i)
                if (wm >> i & 1) {
                    ushort2 pk; pk.x = f2bf(f0[i]); pk.y = f2bf(f1[i]);
                    *(ushort2*)&As[(pg + 16 * i) * LDA + 2 * cp] = pk;
                }
            __syncthreads();
        }
    }

    // ---- epilogue: h = silu(acc + bias) -> Hs[n][p] (bf16), 0 outside image ---
    float biasv[4];
#pragma unroll
    for (int nt = 0; nt < 4; ++nt) biasv[nt] = biasA[nt * 16 + mm];
#pragma unroll
    for (int mt = 0; mt < 3; ++mt) {
        int p0 = (wid * 3 + mt) * 16 + kb * 4;
        bool pv[4];
#pragma unroll
        for (int r = 0; r < 4; ++r) {
            int p = p0 + r;
            int y = (p * 205) >> 11;
            int xx = p - y * 10;
            int gy = ty0 - 1 + y, gx = tx0 - 1 + xx;
            pv[r] = (p < HALO_PX) && gy >= 0 && gy < H_IMG && gx >= 0 && gx < W_IMG;
        }
#pragma unroll
        for (int nt = 0; nt < 4; ++nt) {
            int n = nt * 16 + mm;
            ushort4 o;
            o.x = pv[0] ? f2bf(silu_f(acc[mt][nt][0] + biasv[nt])) : (u16)0;
            o.y = pv[1] ? f2bf(silu_f(acc[mt][nt][1] + biasv[nt])) : (u16)0;
            o.z = pv[2] ? f2bf(silu_f(acc[mt][nt][2] + biasv[nt])) : (u16)0;
            o.w = pv[3] ? f2bf(silu_f(acc[mt][nt][3] + biasv[nt])) : (u16)0;
            *(ushort4*)&Hs[n * LDH + p0] = o;
        }
    }
    __syncthreads();

    // ---- DW 3x3 + BN + SiLU + proto distance; ch split 2-way across halves ---
    int half = tid >> 7, pxl = tid & 127;
    int oy = pxl >> 3, ox = pxl & 7;
    int pb = oy * 10 + ox;

    float norm2 = 0.f;
    float dot[K_PROTO];
#pragma unroll
    for (int kk = 0; kk < K_PROTO; ++kk) dot[kk] = 0.f;

    for (int cl = 0; cl < 32; ++cl) {
        int ch = half * 32 + cl;             // uniform across lanes
        const u16* hc = Hs + ch * LDH;
        const float* wch = dw + ch * 9;      // uniform -> s_load
        float s = 0.f;
#pragma unroll
        for (int dy = 0; dy < 3; ++dy)
#pragma unroll
            for (int dx = 0; dx < 3; ++dx)
                s = fmaf(bf2f(hc[pb + dy * 10 + dx]), wch[dy * 3 + dx], s);
        float g = bn2[ch], bb = bn2[64 + ch], m = bn2[128 + ch], vv = bn2[192 + ch];
        float scale = g * rsqrtf(vv + BN_EPS);
        float val = silu_f(scale * s + (bb - m * scale));
        norm2 = fmaf(val, val, norm2);
#pragma unroll
        for (int kk = 0; kk < K_PROTO; ++kk)
            dot[kk] = fmaf(val, protos[kk * 64 + ch], dot[kk]);
    }

    if (half == 1) {
        float* d = Pp + pxl * 9;
        d[0] = norm2;
#pragma unroll
        for (int kk = 0; kk < K_PROTO; ++kk) d[1 + kk] = dot[kk];
    }
    __syncthreads();

    if (half == 0) {
        const float* sadd = Pp + pxl * 9;
        norm2 += sadd[0];
#pragma unroll
        for (int kk = 0; kk < K_PROTO; ++kk) dot[kk] += sadd[1 + kk];
        float d2min = 1e30f;
#pragma unroll
        for (int kk = 0; kk < K_PROTO; ++kk)
            d2min = fminf(d2min, norm2 + pnorm[kk] - 2.f * dot[kk]);
        float mdv = sqrtf(fmaxf(d2min, 0.f)) * (1.f / 1.000001f);
        md[img * HW + (ty0 + oy) * W_IMG + (tx0 + ox)] = mdv;

        float wmin = mdv, wmax = mdv;
#pragma unroll
        for (int d = 32; d > 0; d >>= 1) {
            wmin = fminf(wmin, __shfl_xor(wmin, d));
            wmax = fmaxf(wmax, __shfl_xor(wmax, d));
        }
        if (lane == 0) {
            mmx[wid * 2]     = wmin;
            mmx[wid * 2 + 1] = wmax;
        }
    }
    __syncthreads();
    if (tid == 0) {
        float bmin = fminf(mmx[0], mmx[2]);
        float bmax = fmaxf(mmx[1], mmx[3]);
        atomicMin(&minmax[img * 2],     __float_as_uint(bmin));
        atomicMax(&minmax[img * 2 + 1], __float_as_uint(bmax));
    }
}

// ---------------- C: normalize deviation + dual DS-conv attention ------------
__global__ __launch_bounds__(256) void attn_kernel(
    const float* __restrict__ md, const unsigned* __restrict__ minmax,
    const float* __restrict__ bs_dw, const float* __restrict__ bs_bn1,
    const float* __restrict__ bs_pw, const float* __restrict__ bs_bn2,
    const float* __restrict__ bl_dw, const float* __restrict__ bl_bn1,
    const float* __restrict__ bl_pw, const float* __restrict__ bl_bn2,
    const float* __restrict__ fuse_w, const float* __restrict__ fuse_b,
    float* __restrict__ attn)
{
    __shared__ float tile[20 * 20];
    int img = blockIdx.x >> 6;
    int t = blockIdx.x & 63;
    int y0 = (t >> 3) << 4, x0 = (t & 7) << 4;
    int tid = threadIdx.x;
    int ty = tid >> 4, tx = tid & 15;

    float fdmin = __uint_as_float(minmax[img * 2]);
    float fdmax = __uint_as_float(minmax[img * 2 + 1]);
    float inv = 1.f / (fdmax - fdmin + 1e-6f);

    const float* mdi = md + img * HW;
    for (int l = tid; l < 400; l += 256) {
        int ly = l / 20, lx = l - ly * 20;
        int yy = y0 - 2 + ly, xx = x0 - 2 + lx;
        float v = 0.f;
        if (yy >= 0 && yy < H_IMG && xx >= 0 && xx < W_IMG)
            v = (mdi[yy * W_IMG + xx] - fdmin) * inv;
        tile[l] = v;
    }
    __syncthreads();

    float c3 = 0.f;
#pragma unroll
    for (int dy = 0; dy < 3; ++dy)
#pragma unroll
        for (int dx = 0; dx < 3; ++dx)
            c3 = fmaf(tile[(ty + 1 + dy) * 20 + tx + 1 + dx], bs_dw[dy * 3 + dx], c3);
    float c5 = 0.f;
#pragma unroll
    for (int dy = 0; dy < 5; ++dy)
#pragma unroll
        for (int dx = 0; dx < 5; ++dx)
            c5 = fmaf(tile[(ty + dy) * 20 + tx + dx], bl_dw[dy * 5 + dx], c5);

    float s1 = bs_bn1[0] * rsqrtf(bs_bn1[3] + BN_EPS);
    float t1 = silu_f(s1 * c3 + (bs_bn1[1] - bs_bn1[2] * s1));
    float s2 = bl_bn1[0] * rsqrtf(bl_bn1[3] + BN_EPS);
    float t2 = silu_f(s2 * c5 + (bl_bn1[1] - bl_bn1[2] * s2));

    float acc = fuse_b[0];
#pragma unroll
    for (int c = 0; c < 8; ++c) {
        float scs = bs_bn2[c] * rsqrtf(bs_bn2[24 + c] + BN_EPS);
        float u1 = silu_f(scs * (bs_pw[c] * t1) + (bs_bn2[8 + c] - bs_bn2[16 + c] * scs));
        acc = fmaf(fuse_w[c], u1, acc);
        float scl = bl_bn2[c] * rsqrtf(bl_bn2[24 + c] + BN_EPS);
        float u2 = silu_f(scl * (bl_pw[c] * t2) + (bl_bn2[8 + c] - bl_bn2[16 + c] * scl));
        acc = fmaf(fuse_w[8 + c], u2, acc);
    }
    float a = 1.f / (1.f + __expf(-acc));
    attn[img * HW + (y0 + ty) * W_IMG + (x0 + tx)] = a;
}

// ---------------- D: out = x * (1 + gamma * attn) ----------------------------
__global__ __launch_bounds__(256) void final_kernel(
    const float* __restrict__ x, const float* __restrict__ attn,
    const float* __restrict__ gamma, float* __restrict__ out)
{
    size_t i = ((size_t)blockIdx.x * 256 + (size_t)threadIdx.x) * 4;
    float g = gamma[0];
    int b = (int)(i / ((size_t)C_IN * HW));
    int hw = (int)(i % HW);
    const float4 xv = *(const float4*)(x + i);
    const float4 av = *(const float4*)(attn + (size_t)b * HW + hw);
    float4 o;
    o.x = xv.x * (1.f + g * av.x);
    o.y = xv.y * (1.f + g * av.y);
    o.z = xv.z * (1.f + g * av.z);
    o.w = xv.w * (1.f + g * av.w);
    *(float4*)(out + i) = o;
}

extern "C" void kernel_launch(void* const* d_in, const int* in_sizes, int n_in,
                              void* d_out, int out_size, void* d_ws, size_t ws_size,
                              hipStream_t stream) {
    const float* x      = (const float*)d_in[0];
    const float* fp_w1  = (const float*)d_in[1];
    const float* fp_bn1 = (const float*)d_in[2];
    const float* fp_dw  = (const float*)d_in[3];
    const float* fp_bn2 = (const float*)d_in[4];
    const float* protos = (const float*)d_in[5];
    const float* bs_dw  = (const float*)d_in[6];
    const float* bs_bn1 = (const float*)d_in[7];
    const float* bs_pw  = (const float*)d_in[8];
    const float* bs_bn2 = (const float*)d_in[9];
    const float* bl_dw  = (const float*)d_in[10];
    const float* bl_bn1 = (const float*)d_in[11];
    const float* bl_pw  = (const float*)d_in[12];
    const float* bl_bn2 = (const float*)d_in[13];
    const float* fuse_w = (const float*)d_in[14];
    const float* fuse_b = (const float*)d_in[15];
    const float* gamma  = (const float*)d_in[16];
    float* ws  = (float*)d_ws;
    float* out = (float*)d_out;

    prep_kernel<<<65, 256, 0, stream>>>(fp_w1, fp_bn1, protos, ws);
    fused_front_kernel<<<512, 256, 0, stream>>>(x, (const u16*)(ws + OFF_WTBF),
                                                ws + OFF_BIASA, fp_dw, fp_bn2, protos,
                                                ws + OFF_PNORM, ws + OFF_MD,
                                                (unsigned*)(ws + OFF_MINMAX));
    attn_kernel<<<256, 256, 0, stream>>>(ws + OFF_MD, (const unsigned*)(ws + OFF_MINMAX),
                                         bs_dw, bs_bn1, bs_pw, bs_bn2,
                                         bl_dw, bl_bn1, bl_pw, bl_bn2,
                                         fuse_w, fuse_b, ws + OFF_ATTN);
    final_kernel<<<16384, 256, 0, stream>>>(x, ws + OFF_ATTN, gamma, out);
}